// Round 5
// baseline (61.132 us; speedup 1.0000x reference)
//
#include <hip/hip_runtime.h>
#include <math.h>

#define B_ 2
#define N_ 8192
#define M_ 8192
#define KSEL 7782          // int(N * 0.95)
#define CH 16              // chunks over M
#define CHS (M_ / CH)      // 512 targets per chunk
#define PTS 512            // points per block (256 threads x 2)

// ---- order-preserving float <-> u32 encoding (ascending) ----
__device__ __forceinline__ unsigned ord_of(float f) {
  unsigned u = __float_as_uint(f);
  return (u & 0x80000000u) ? ~u : (u | 0x80000000u);
}
__device__ __forceinline__ float float_of_ord(unsigned o) {
  unsigned u = (o & 0x80000000u) ? (o ^ 0x80000000u) : ~o;
  return __uint_as_float(u);
}

// ===== kernel 0: init keys + precompute target squared norms ==================
// grid: B_*M_/256 blocks. Coalesced u64 stores + tnorm[j] = |xt_j|^2.
__global__ __launch_bounds__(256) void init_kernel(
    unsigned long long* __restrict__ keys, const float* __restrict__ xt,
    float* __restrict__ tnorm) {
  const int gid = blockIdx.x * 256 + threadIdx.x;
  keys[gid] = 0xFFFFFFFFFFFFFFFFull;
  float tx = xt[gid * 3 + 0], ty = xt[gid * 3 + 1], tz = xt[gid * 3 + 2];
  tnorm[gid] = tx * tx + ty * ty + tz * tz;
}

// ================= kernel 1: brute-force NN (min d2 + argmin) =================
// No LDS: target coords/norms are wave-uniform per iteration -> scalar loads
// (s_load via K$) that co-issue with VALU. Hot loop is 13 VALU / j for 2 pts.
// n0 (per-point const) is added after the loop (monotone, preserves argmin).
__global__ __launch_bounds__(256) void nn_kernel(
    const float* __restrict__ xp, const float* __restrict__ xt,
    const float* __restrict__ tnorm, unsigned long long* __restrict__ keys) {
  const int b = blockIdx.z;
  const int pblk = blockIdx.x;
  const int ch = blockIdx.y;

  const float* __restrict__ xtb = xt + ((size_t)b * M_ + (size_t)ch * CHS) * 3;
  const float* __restrict__ twb = tnorm + (size_t)b * M_ + (size_t)ch * CHS;

  const int i0 = pblk * PTS + threadIdx.x;
  const int i1 = i0 + 256;
  const float* p0 = xp + ((size_t)b * N_ + i0) * 3;
  const float* p1 = xp + ((size_t)b * N_ + i1) * 3;
  float x0 = p0[0], y0 = p0[1], z0 = p0[2];
  float x1 = p1[0], y1 = p1[1], z1 = p1[2];
  float n0 = x0 * x0 + y0 * y0 + z0 * z0;
  float n1 = x1 * x1 + y1 * y1 + z1 * z1;
  float xm0 = -2.0f * x0, ym0 = -2.0f * y0, zm0 = -2.0f * z0;
  float xm1 = -2.0f * x1, ym1 = -2.0f * y1, zm1 = -2.0f * z1;

  float best0 = 3.4e38f, best1 = 3.4e38f;
  int bi0 = 0, bi1 = 0;
#pragma unroll 8
  for (int j = 0; j < CHS; ++j) {
    float tx = xtb[3 * j + 0];
    float ty = xtb[3 * j + 1];
    float tz = xtb[3 * j + 2];
    float tw = twb[j];
    float d0 = fmaf(tx, xm0, fmaf(ty, ym0, fmaf(tz, zm0, tw)));
    float d1 = fmaf(tx, xm1, fmaf(ty, ym1, fmaf(tz, zm1, tw)));
    if (d0 < best0) { best0 = d0; bi0 = j; }
    if (d1 < best1) { best1 = d1; bi1 = j; }
  }
  best0 += n0;
  best1 += n1;

  const int base = ch * CHS;
  unsigned long long k0 =
      ((unsigned long long)ord_of(best0) << 32) | (unsigned)(base + bi0);
  unsigned long long k1 =
      ((unsigned long long)ord_of(best1) << 32) | (unsigned)(base + bi1);
  atomicMin(&keys[(size_t)b * N_ + i0], k0);
  atomicMin(&keys[(size_t)b * N_ + i1], k1);
}

// ============ kernel 2: k-th order statistic via 4-pass radix select ==========
// Also zeroes the 32-double accumulator slab for its batch.
__global__ __launch_bounds__(1024) void sel_kernel(
    const unsigned long long* __restrict__ keys, float* __restrict__ mout,
    double* __restrict__ acc) {
  __shared__ unsigned hist[256];
  __shared__ unsigned sel_digit, sel_rank;
  const int b = blockIdx.x;

  if (threadIdx.x < 32) acc[b * 32 + threadIdx.x] = 0.0;

  unsigned v[8];
#pragma unroll
  for (int t = 0; t < 8; ++t)
    v[t] = (unsigned)(keys[(size_t)b * N_ + threadIdx.x + t * 1024] >> 32);

  unsigned prefix = 0;
  unsigned rank = KSEL;

#pragma unroll
  for (int pass = 0; pass < 4; ++pass) {
    const int shift = 24 - pass * 8;
    const unsigned pmask = (pass == 0) ? 0u : (0xFFFFFFFFu << (shift + 8));

    if (threadIdx.x < 256) hist[threadIdx.x] = 0;
    __syncthreads();

#pragma unroll
    for (int t = 0; t < 8; ++t) {
      if ((v[t] & pmask) == prefix)
        atomicAdd(&hist[(v[t] >> shift) & 0xFFu], 1u);
    }
    __syncthreads();

    if (threadIdx.x < 64) {
      const int lane = threadIdx.x;
      unsigned h0 = hist[lane * 4 + 0], h1 = hist[lane * 4 + 1];
      unsigned h2 = hist[lane * 4 + 2], h3 = hist[lane * 4 + 3];
      unsigned c0 = h0, c1 = c0 + h1, c2 = c1 + h2, c3 = c2 + h3;
      unsigned s = c3;
#pragma unroll
      for (int off = 1; off < 64; off <<= 1) {
        unsigned t = __shfl_up(s, off);
        if (lane >= off) s += t;
      }
      unsigned excl = s - c3;  // exclusive prefix of this lane's 4 bins
      unsigned r = rank;
      if (r >= excl && r < excl + c0) { sel_digit = lane * 4 + 0; sel_rank = r - excl; }
      if (r >= excl + c0 && r < excl + c1) { sel_digit = lane * 4 + 1; sel_rank = r - (excl + c0); }
      if (r >= excl + c1 && r < excl + c2) { sel_digit = lane * 4 + 2; sel_rank = r - (excl + c1); }
      if (r >= excl + c2 && r < excl + c3) { sel_digit = lane * 4 + 3; sel_rank = r - (excl + c2); }
    }
    __syncthreads();
    prefix |= (sel_digit << shift);
    rank = sel_rank;
    __syncthreads();
  }

  if (threadIdx.x == 0) {
    float f = float_of_ord(prefix);
    mout[b] = fmaxf(f, 1.0f);
  }
}

// ---- span_cov: 7 params -> 3x3 covariance (E diag(e) E^T) ----
__device__ __forceinline__ void cov_from_params(const float* __restrict__ c,
                                                float C[3][3]) {
  float e0 = c[0];
  float e1 = e0 + c[1];
  float e2 = e1 + c[2];
  float qx = c[3], qy = c[4], qz = c[5], qw = c[6];
  float qn = sqrtf(qx * qx + qy * qy + qz * qz + qw * qw) + 1e-9f;
  float x = qx / qn, y = qy / qn, z = qz / qn, w = qw / qn;
  float E[3][3];
  E[0][0] = 1.0f - 2.0f * (y * y + z * z);
  E[0][1] = 2.0f * (x * y - z * w);
  E[0][2] = 2.0f * (x * z + y * w);
  E[1][0] = 2.0f * (x * y + z * w);
  E[1][1] = 1.0f - 2.0f * (x * x + z * z);
  E[1][2] = 2.0f * (y * z - x * w);
  E[2][0] = 2.0f * (x * z - y * w);
  E[2][1] = 2.0f * (y * z + x * w);
  E[2][2] = 1.0f - 2.0f * (x * x + y * y);
#pragma unroll
  for (int i = 0; i < 3; ++i)
#pragma unroll
    for (int k = 0; k < 3; ++k)
      C[i][k] = e0 * E[i][0] * E[k][0] + e1 * E[i][1] * E[k][1] +
                e2 * E[i][2] * E[k][2];
}

// ================= kernel 3: per-point pass + 19-way reduction =================
__global__ __launch_bounds__(256) void main_kernel(
    const float* __restrict__ xp, const float* __restrict__ xt,
    const float* __restrict__ cpp, const float* __restrict__ ctp,
    const float* __restrict__ Rp, const float* __restrict__ nrm,
    const unsigned long long* __restrict__ keys, const float* __restrict__ mout,
    double* __restrict__ acc) {
  const int b = blockIdx.y;
  const int i = blockIdx.x * 256 + threadIdx.x;

  float R[3][3];
#pragma unroll
  for (int r = 0; r < 3; ++r)
#pragma unroll
    for (int c = 0; c < 3; ++c) R[r][c] = Rp[b * 9 + r * 3 + c];
  const float m = mout[b];

  unsigned long long key = keys[(size_t)b * N_ + i];
  float d2 = float_of_ord((unsigned)(key >> 32));
  int id = (int)(key & 0xFFFFFFFFull);

  const float* p = xp + ((size_t)b * N_ + i) * 3;
  float px = p[0], py = p[1], pz = p[2];
  const float* a_ = xt + ((size_t)b * M_ + id) * 3;
  float ax = a_[0], ay = a_[1], az = a_[2];

  float cmv = (d2 < m) ? 1.0f : 0.0f;

  float Cp[3][3], Ct[3][3];
  cov_from_params(cpp + ((size_t)b * N_ + i) * 7, Cp);
  cov_from_params(ctp + ((size_t)b * M_ + id) * 7, Ct);

  // G = Cp + R Ct R^T
  float T[3][3], G[3][3];
#pragma unroll
  for (int r = 0; r < 3; ++r)
#pragma unroll
    for (int c = 0; c < 3; ++c)
      T[r][c] = R[r][0] * Ct[0][c] + R[r][1] * Ct[1][c] + R[r][2] * Ct[2][c];
#pragma unroll
  for (int r = 0; r < 3; ++r)
#pragma unroll
    for (int c = 0; c < 3; ++c)
      G[r][c] = Cp[r][c] +
                (T[r][0] * R[c][0] + T[r][1] * R[c][1] + T[r][2] * R[c][2]);

  // inverse via adjugate
  float c00 = G[1][1] * G[2][2] - G[1][2] * G[2][1];
  float c01 = G[1][2] * G[2][0] - G[1][0] * G[2][2];
  float c02 = G[1][0] * G[2][1] - G[1][1] * G[2][0];
  float det = G[0][0] * c00 + G[0][1] * c01 + G[0][2] * c02;
  float rdet = 1.0f / det;
  float i00 = (G[1][1] * G[2][2] - G[1][2] * G[2][1]) * rdet;
  float i01 = (G[0][2] * G[2][1] - G[0][1] * G[2][2]) * rdet;
  float i02 = (G[0][1] * G[1][2] - G[0][2] * G[1][1]) * rdet;
  float i10 = (G[1][2] * G[2][0] - G[1][0] * G[2][2]) * rdet;
  float i11 = (G[0][0] * G[2][2] - G[0][2] * G[2][0]) * rdet;
  float i12 = (G[0][2] * G[1][0] - G[0][0] * G[1][2]) * rdet;
  float i20 = (G[1][0] * G[2][1] - G[1][1] * G[2][0]) * rdet;
  float i21 = (G[0][1] * G[2][0] - G[0][0] * G[2][1]) * rdet;
  float i22 = (G[0][0] * G[1][1] - G[0][1] * G[1][0]) * rdet;

  float dvx = px - ax, dvy = py - ay, dvz = pz - az;
  float t0 = i00 * dvx + i01 * dvy + i02 * dvz;
  float t1 = i10 * dvx + i11 * dvy + i12 * dvz;
  float t2 = i20 * dvx + i21 * dvy + i22 * dvz;
  float sq = dvx * t0 + dvy * t1 + dvz * t2;
  float logdet = logf(det);

  const float* nv = nrm + ((size_t)b * N_ + i) * 3;
  float nx = nv[0], ny = nv[1], nz = nv[2];
  float gx = ax - px, gy = ay - py, gz = az - pz;
  float dt = nx * gx + ny * gy + nz * gz;
  float den = fmaxf(sqrtf(nx * nx + ny * ny + nz * nz) *
                        sqrtf(gx * gx + gy * gy + gz * gz),
                    1e-8f);
  float cs = dt / den;
  float w = cs * cs * cmv;

  double vals[19];
  vals[0] = (double)cmv;
  vals[1] = (double)(sq) * (double)cmv;
  vals[2] = (double)(logdet) * (double)cmv;
  vals[3] = (double)w;
  vals[4] = (double)w * px;
  vals[5] = (double)w * py;
  vals[6] = (double)w * pz;
  vals[7] = (double)w * ax;
  vals[8] = (double)w * ay;
  vals[9] = (double)w * az;
  float pr[3] = {px, py, pz}, ar[3] = {ax, ay, az};
#pragma unroll
  for (int r = 0; r < 3; ++r)
#pragma unroll
    for (int c = 0; c < 3; ++c)
      vals[10 + r * 3 + c] = (double)w * (double)pr[r] * (double)ar[c];

  // wave reduce (64 lanes)
#pragma unroll
  for (int off = 32; off > 0; off >>= 1) {
#pragma unroll
    for (int k = 0; k < 19; ++k) vals[k] += __shfl_down(vals[k], off);
  }
  __shared__ double red[4][19];
  const int lane = threadIdx.x & 63, wv = threadIdx.x >> 6;
  if (lane == 0) {
#pragma unroll
    for (int k = 0; k < 19; ++k) red[wv][k] = vals[k];
  }
  __syncthreads();
  if (threadIdx.x < 19) {
    double s = red[0][threadIdx.x] + red[1][threadIdx.x] +
               red[2][threadIdx.x] + red[3][threadIdx.x];
    atomicAdd(&acc[b * 32 + threadIdx.x], s);
  }
}

// ====================== kernel 4: finalize (loss + Kabsch) =====================
__device__ double det3(const double M[3][3]) {
  return M[0][0] * (M[1][1] * M[2][2] - M[1][2] * M[2][1]) -
         M[0][1] * (M[1][0] * M[2][2] - M[1][2] * M[2][0]) +
         M[0][2] * (M[1][0] * M[2][1] - M[1][1] * M[2][0]);
}

// robust eigenvector of symmetric A for eigenvalue lam: largest cross product
// of rows of (A - lam I)
__device__ void eigvec3(const double A[3][3], double lam, double v[3]) {
  double r[3][3];
#pragma unroll
  for (int i = 0; i < 3; ++i) {
#pragma unroll
    for (int j = 0; j < 3; ++j) r[i][j] = A[i][j];
    r[i][i] -= lam;
  }
  double c01[3] = {r[0][1] * r[1][2] - r[0][2] * r[1][1],
                   r[0][2] * r[1][0] - r[0][0] * r[1][2],
                   r[0][0] * r[1][1] - r[0][1] * r[1][0]};
  double c02[3] = {r[0][1] * r[2][2] - r[0][2] * r[2][1],
                   r[0][2] * r[2][0] - r[0][0] * r[2][2],
                   r[0][0] * r[2][1] - r[0][1] * r[2][0]};
  double c12[3] = {r[1][1] * r[2][2] - r[1][2] * r[2][1],
                   r[1][2] * r[2][0] - r[1][0] * r[2][2],
                   r[1][0] * r[2][1] - r[1][1] * r[2][0]};
  double n01 = c01[0] * c01[0] + c01[1] * c01[1] + c01[2] * c01[2];
  double n02 = c02[0] * c02[0] + c02[1] * c02[1] + c02[2] * c02[2];
  double n12 = c12[0] * c12[0] + c12[1] * c12[1] + c12[2] * c12[2];
  double* best = c01;
  double bn = n01;
  if (n02 > bn) { best = c02; bn = n02; }
  if (n12 > bn) { best = c12; bn = n12; }
  double inv = (bn > 0.0) ? 1.0 / sqrt(bn) : 0.0;
  v[0] = best[0] * inv;
  v[1] = best[1] * inv;
  v[2] = best[2] * inv;
  if (inv == 0.0) v[0] = 1.0;  // degenerate fallback
}

// Kabsch via closed-form symmetric 3x3 eigendecomposition of A = H^T H.
__device__ void kabsch(const double H[3][3], double R[3][3]) {
  double A[3][3];
  for (int i = 0; i < 3; ++i)
    for (int j = 0; j < 3; ++j)
      A[i][j] = H[0][i] * H[0][j] + H[1][i] * H[1][j] + H[2][i] * H[2][j];

  double lam[3];
  double Vs[3][3];
  double mtr = (A[0][0] + A[1][1] + A[2][2]) / 3.0;
  double K00 = A[0][0] - mtr, K11 = A[1][1] - mtr, K22 = A[2][2] - mtr;
  double a01 = A[0][1], a02 = A[0][2], a12 = A[1][2];
  double p2 = K00 * K00 + K11 * K11 + K22 * K22 +
              2.0 * (a01 * a01 + a02 * a02 + a12 * a12);
  double p = sqrt(p2 / 6.0);
  if (p < 1e-100) {
    lam[0] = lam[1] = lam[2] = mtr;
    for (int i = 0; i < 3; ++i)
      for (int j = 0; j < 3; ++j) Vs[i][j] = (i == j) ? 1.0 : 0.0;
  } else {
    double detK = K00 * (K11 * K22 - a12 * a12) -
                  a01 * (a01 * K22 - a12 * a02) +
                  a02 * (a01 * a12 - K11 * a02);
    double rr = detK / (2.0 * p * p * p);
    rr = fmin(1.0, fmax(-1.0, rr));
    double phi = acos(rr) / 3.0;
    lam[0] = mtr + 2.0 * p * cos(phi);                        // largest
    lam[2] = mtr + 2.0 * p * cos(phi + 2.0943951023931953);   // smallest
    lam[1] = 3.0 * mtr - lam[0] - lam[2];                     // middle

    double v0[3], v1[3];
    eigvec3(A, lam[0], v0);
    eigvec3(A, lam[1], v1);
    double dp = v1[0] * v0[0] + v1[1] * v0[1] + v1[2] * v0[2];
    v1[0] -= dp * v0[0];
    v1[1] -= dp * v0[1];
    v1[2] -= dp * v0[2];
    double n1 = v1[0] * v1[0] + v1[1] * v1[1] + v1[2] * v1[2];
    if (n1 > 1e-200) {
      double inv = 1.0 / sqrt(n1);
      v1[0] *= inv; v1[1] *= inv; v1[2] *= inv;
    } else {
      double ax = fabs(v0[0]), ay = fabs(v0[1]), az = fabs(v0[2]);
      double t[3] = {0, 0, 0};
      if (ax <= ay && ax <= az) t[0] = 1.0;
      else if (ay <= az) t[1] = 1.0;
      else t[2] = 1.0;
      v1[0] = v0[1] * t[2] - v0[2] * t[1];
      v1[1] = v0[2] * t[0] - v0[0] * t[2];
      v1[2] = v0[0] * t[1] - v0[1] * t[0];
      double inv = 1.0 / sqrt(v1[0] * v1[0] + v1[1] * v1[1] + v1[2] * v1[2]);
      v1[0] *= inv; v1[1] *= inv; v1[2] *= inv;
    }
    double v2[3] = {v0[1] * v1[2] - v0[2] * v1[1],
                    v0[2] * v1[0] - v0[0] * v1[2],
                    v0[0] * v1[1] - v0[1] * v1[0]};
    for (int i = 0; i < 3; ++i) {
      Vs[i][0] = v0[i];
      Vs[i][1] = v1[i];
      Vs[i][2] = v2[i];
    }
  }

  double sg[3];
  for (int c = 0; c < 3; ++c) sg[c] = sqrt(fmax(lam[c], 0.0));

  double U[3][3];
  for (int c = 0; c < 3; ++c) {
    double ux = H[0][0] * Vs[0][c] + H[0][1] * Vs[1][c] + H[0][2] * Vs[2][c];
    double uy = H[1][0] * Vs[0][c] + H[1][1] * Vs[1][c] + H[1][2] * Vs[2][c];
    double uz = H[2][0] * Vs[0][c] + H[2][1] * Vs[1][c] + H[2][2] * Vs[2][c];
    double inv = (sg[c] > 1e-12 * sg[0] + 1e-300) ? 1.0 / sg[c] : 0.0;
    U[0][c] = ux * inv;
    U[1][c] = uy * inv;
    U[2][c] = uz * inv;
  }
  if (sg[2] <= 1e-12 * sg[0] + 1e-300) {
    U[0][2] = U[1][0] * U[2][1] - U[2][0] * U[1][1];
    U[1][2] = U[2][0] * U[0][1] - U[0][0] * U[2][1];
    U[2][2] = U[0][0] * U[1][1] - U[1][0] * U[0][1];
  }
  double d = det3(U) * det3(Vs);
  for (int i = 0; i < 3; ++i)
    for (int j = 0; j < 3; ++j)
      R[i][j] = Vs[i][0] * U[j][0] + Vs[i][1] * U[j][1] + d * Vs[i][2] * U[j][2];
}

__global__ __launch_bounds__(64) void finalize_kernel(
    const double* __restrict__ acc, float* __restrict__ out) {
  __shared__ double lossb[B_];
  const int b = threadIdx.x;
  if (b < B_) {
    const double* a = acc + b * 32;
    double cnt = a[0], ssq = a[1], sld = a[2], W = a[3];
    double loss = ssq / cnt + 0.001 * 0.5 * sld / cnt;
    lossb[b] = loss;
    double Ss[3] = {a[4], a[5], a[6]}, St[3] = {a[7], a[8], a[9]};
    double sc[3], tc[3];
    for (int c = 0; c < 3; ++c) { sc[c] = Ss[c] / W; tc[c] = St[c] / W; }
    double H[3][3];
    for (int i = 0; i < 3; ++i)
      for (int j = 0; j < 3; ++j)
        H[i][j] = a[10 + i * 3 + j] - Ss[i] * St[j] / W;
    double Rm[3][3];
    kabsch(H, Rm);
    for (int i = 0; i < 3; ++i)
      for (int j = 0; j < 3; ++j)
        out[1 + b * 9 + i * 3 + j] = (float)Rm[i][j];
    for (int i = 0; i < 3; ++i) {
      double t =
          tc[i] - (Rm[i][0] * sc[0] + Rm[i][1] * sc[1] + Rm[i][2] * sc[2]);
      out[1 + B_ * 9 + b * 3 + i] = (float)t;
    }
  }
  __syncthreads();
  if (threadIdx.x == 0) out[0] = (float)(lossb[0] + lossb[1]);
}

// ================================ launcher ====================================
extern "C" void kernel_launch(void* const* d_in, const int* in_sizes, int n_in,
                              void* d_out, int out_size, void* d_ws,
                              size_t ws_size, hipStream_t stream) {
  const float* xyz_pred = (const float*)d_in[0];
  const float* xyz_target = (const float*)d_in[1];
  const float* cov_pred = (const float*)d_in[2];
  const float* cov_target = (const float*)d_in[3];
  const float* R_pred = (const float*)d_in[4];
  // d_in[5] t_pred unused, d_in[7] normal_target unused
  const float* normal_pred = (const float*)d_in[6];
  float* out = (float*)d_out;

  char* ws = (char*)d_ws;
  double* acc = (double*)ws;                                   // B*32 doubles
  unsigned long long* keys = (unsigned long long*)(ws + 512);  // B*N u64
  float* mout = (float*)(ws + 512 + (size_t)B_ * N_ * 8);      // B floats
  float* tnorm = (float*)(ws + 1024 + (size_t)B_ * N_ * 8);    // B*M floats

  hipLaunchKernelGGL(init_kernel, dim3(B_ * M_ / 256), dim3(256), 0, stream,
                     keys, xyz_target, tnorm);
  hipLaunchKernelGGL(nn_kernel, dim3(N_ / PTS, CH, B_), dim3(256), 0, stream,
                     xyz_pred, xyz_target, tnorm, keys);
  hipLaunchKernelGGL(sel_kernel, dim3(B_), dim3(1024), 0, stream, keys, mout,
                     acc);
  hipLaunchKernelGGL(main_kernel, dim3(N_ / 256, B_), dim3(256), 0, stream,
                     xyz_pred, xyz_target, cov_pred, cov_target, R_pred,
                     normal_pred, keys, mout, acc);
  hipLaunchKernelGGL(finalize_kernel, dim3(1), dim3(64), 0, stream, acc, out);
}

// Round 6
// 45.724 us; speedup vs baseline: 1.3370x; 1.3370x over previous
//
#include <hip/hip_runtime.h>
#include <math.h>

#define B_ 2
#define N_ 8192
#define M_ 8192
#define KSEL 7782          // int(N * 0.95)
#define CH 128             // chunks over M
#define CHS (M_ / CH)      // 64 targets per chunk
#define PTS 1024           // points per block (256 threads x 4)

// ---- order-preserving float <-> u32 encoding (ascending) ----
__device__ __forceinline__ unsigned ord_of(float f) {
  unsigned u = __float_as_uint(f);
  return (u & 0x80000000u) ? ~u : (u | 0x80000000u);
}
__device__ __forceinline__ float float_of_ord(unsigned o) {
  unsigned u = (o & 0x80000000u) ? (o ^ 0x80000000u) : ~o;
  return __uint_as_float(u);
}

// ===== kernel 0: init keys + precompute target squared norms ==================
__global__ __launch_bounds__(256) void init_kernel(
    unsigned long long* __restrict__ keys, const float* __restrict__ xt,
    float* __restrict__ tnorm) {
  const int gid = blockIdx.x * 256 + threadIdx.x;
  keys[gid] = 0xFFFFFFFFFFFFFFFFull;
  float tx = xt[gid * 3 + 0], ty = xt[gid * 3 + 1], tz = xt[gid * 3 + 2];
  tnorm[gid] = tx * tx + ty * ty + tz * tz;
}

// ================= kernel 1: brute-force NN (min d2 + argmin) =================
// LDS broadcast reads (conflict-free), 4 pts/thread so one ds_read_b128 feeds
// 4x64 pairs; 2048 blocks -> 8 blocks/CU for latency hiding. n0 added after
// the loop (monotone, preserves argmin).
__global__ __launch_bounds__(256, 8) void nn_kernel(
    const float* __restrict__ xp, const float* __restrict__ xt,
    const float* __restrict__ tnorm, unsigned long long* __restrict__ keys) {
  const int b = blockIdx.z;
  const int pblk = blockIdx.x;
  const int ch = blockIdx.y;

  __shared__ float4 tg[CHS];
  const float* __restrict__ xtb = xt + ((size_t)b * M_ + (size_t)ch * CHS) * 3;
  const float* __restrict__ twb = tnorm + (size_t)b * M_ + (size_t)ch * CHS;
  if (threadIdx.x < CHS) {
    const int j = threadIdx.x;
    tg[j] = make_float4(xtb[3 * j + 0], xtb[3 * j + 1], xtb[3 * j + 2],
                        twb[j]);
  }
  __syncthreads();

  const int i0 = pblk * PTS + threadIdx.x;  // points i0 + k*256, k=0..3
  float xm[4], ym[4], zm[4], nrm2[4], best[4];
  int bi[4];
#pragma unroll
  for (int k = 0; k < 4; ++k) {
    const float* p = xp + ((size_t)b * N_ + i0 + k * 256) * 3;
    float x = p[0], y = p[1], z = p[2];
    nrm2[k] = x * x + y * y + z * z;
    xm[k] = -2.0f * x;
    ym[k] = -2.0f * y;
    zm[k] = -2.0f * z;
    best[k] = 3.4e38f;
    bi[k] = 0;
  }

#pragma unroll 2
  for (int j = 0; j < CHS; ++j) {
    float4 t = tg[j];
#pragma unroll
    for (int k = 0; k < 4; ++k) {
      float d = fmaf(t.x, xm[k], fmaf(t.y, ym[k], fmaf(t.z, zm[k], t.w)));
      if (d < best[k]) { best[k] = d; bi[k] = j; }
    }
  }

  const int base = ch * CHS;
#pragma unroll
  for (int k = 0; k < 4; ++k) {
    unsigned long long key =
        ((unsigned long long)ord_of(best[k] + nrm2[k]) << 32) |
        (unsigned)(base + bi[k]);
    atomicMin(&keys[(size_t)b * N_ + i0 + k * 256], key);
  }
}

// ============ kernel 2: k-th order statistic via 4-pass radix select ==========
// Also zeroes the 32-double accumulator slab for its batch.
__global__ __launch_bounds__(1024) void sel_kernel(
    const unsigned long long* __restrict__ keys, float* __restrict__ mout,
    double* __restrict__ acc) {
  __shared__ unsigned hist[256];
  __shared__ unsigned sel_digit, sel_rank;
  const int b = blockIdx.x;

  if (threadIdx.x < 32) acc[b * 32 + threadIdx.x] = 0.0;

  unsigned v[8];
#pragma unroll
  for (int t = 0; t < 8; ++t)
    v[t] = (unsigned)(keys[(size_t)b * N_ + threadIdx.x + t * 1024] >> 32);

  unsigned prefix = 0;
  unsigned rank = KSEL;

#pragma unroll
  for (int pass = 0; pass < 4; ++pass) {
    const int shift = 24 - pass * 8;
    const unsigned pmask = (pass == 0) ? 0u : (0xFFFFFFFFu << (shift + 8));

    if (threadIdx.x < 256) hist[threadIdx.x] = 0;
    __syncthreads();

#pragma unroll
    for (int t = 0; t < 8; ++t) {
      if ((v[t] & pmask) == prefix)
        atomicAdd(&hist[(v[t] >> shift) & 0xFFu], 1u);
    }
    __syncthreads();

    if (threadIdx.x < 64) {
      const int lane = threadIdx.x;
      unsigned h0 = hist[lane * 4 + 0], h1 = hist[lane * 4 + 1];
      unsigned h2 = hist[lane * 4 + 2], h3 = hist[lane * 4 + 3];
      unsigned c0 = h0, c1 = c0 + h1, c2 = c1 + h2, c3 = c2 + h3;
      unsigned s = c3;
#pragma unroll
      for (int off = 1; off < 64; off <<= 1) {
        unsigned t = __shfl_up(s, off);
        if (lane >= off) s += t;
      }
      unsigned excl = s - c3;  // exclusive prefix of this lane's 4 bins
      unsigned r = rank;
      if (r >= excl && r < excl + c0) { sel_digit = lane * 4 + 0; sel_rank = r - excl; }
      if (r >= excl + c0 && r < excl + c1) { sel_digit = lane * 4 + 1; sel_rank = r - (excl + c0); }
      if (r >= excl + c1 && r < excl + c2) { sel_digit = lane * 4 + 2; sel_rank = r - (excl + c1); }
      if (r >= excl + c2 && r < excl + c3) { sel_digit = lane * 4 + 3; sel_rank = r - (excl + c2); }
    }
    __syncthreads();
    prefix |= (sel_digit << shift);
    rank = sel_rank;
    __syncthreads();
  }

  if (threadIdx.x == 0) {
    float f = float_of_ord(prefix);
    mout[b] = fmaxf(f, 1.0f);
  }
}

// ---- span_cov: 7 params -> 3x3 covariance (E diag(e) E^T) ----
__device__ __forceinline__ void cov_from_params(const float* __restrict__ c,
                                                float C[3][3]) {
  float e0 = c[0];
  float e1 = e0 + c[1];
  float e2 = e1 + c[2];
  float qx = c[3], qy = c[4], qz = c[5], qw = c[6];
  float qn = sqrtf(qx * qx + qy * qy + qz * qz + qw * qw) + 1e-9f;
  float x = qx / qn, y = qy / qn, z = qz / qn, w = qw / qn;
  float E[3][3];
  E[0][0] = 1.0f - 2.0f * (y * y + z * z);
  E[0][1] = 2.0f * (x * y - z * w);
  E[0][2] = 2.0f * (x * z + y * w);
  E[1][0] = 2.0f * (x * y + z * w);
  E[1][1] = 1.0f - 2.0f * (x * x + z * z);
  E[1][2] = 2.0f * (y * z - x * w);
  E[2][0] = 2.0f * (x * z - y * w);
  E[2][1] = 2.0f * (y * z + x * w);
  E[2][2] = 1.0f - 2.0f * (x * x + y * y);
#pragma unroll
  for (int i = 0; i < 3; ++i)
#pragma unroll
    for (int k = 0; k < 3; ++k)
      C[i][k] = e0 * E[i][0] * E[k][0] + e1 * E[i][1] * E[k][1] +
                e2 * E[i][2] * E[k][2];
}

// ================= kernel 3: per-point pass + 19-way reduction =================
__global__ __launch_bounds__(256) void main_kernel(
    const float* __restrict__ xp, const float* __restrict__ xt,
    const float* __restrict__ cpp, const float* __restrict__ ctp,
    const float* __restrict__ Rp, const float* __restrict__ nrm,
    const unsigned long long* __restrict__ keys, const float* __restrict__ mout,
    double* __restrict__ acc) {
  const int b = blockIdx.y;
  const int i = blockIdx.x * 256 + threadIdx.x;

  float R[3][3];
#pragma unroll
  for (int r = 0; r < 3; ++r)
#pragma unroll
    for (int c = 0; c < 3; ++c) R[r][c] = Rp[b * 9 + r * 3 + c];
  const float m = mout[b];

  unsigned long long key = keys[(size_t)b * N_ + i];
  float d2 = float_of_ord((unsigned)(key >> 32));
  int id = (int)(key & 0xFFFFFFFFull);

  const float* p = xp + ((size_t)b * N_ + i) * 3;
  float px = p[0], py = p[1], pz = p[2];
  const float* a_ = xt + ((size_t)b * M_ + id) * 3;
  float ax = a_[0], ay = a_[1], az = a_[2];

  float cmv = (d2 < m) ? 1.0f : 0.0f;

  float Cp[3][3], Ct[3][3];
  cov_from_params(cpp + ((size_t)b * N_ + i) * 7, Cp);
  cov_from_params(ctp + ((size_t)b * M_ + id) * 7, Ct);

  // G = Cp + R Ct R^T
  float T[3][3], G[3][3];
#pragma unroll
  for (int r = 0; r < 3; ++r)
#pragma unroll
    for (int c = 0; c < 3; ++c)
      T[r][c] = R[r][0] * Ct[0][c] + R[r][1] * Ct[1][c] + R[r][2] * Ct[2][c];
#pragma unroll
  for (int r = 0; r < 3; ++r)
#pragma unroll
    for (int c = 0; c < 3; ++c)
      G[r][c] = Cp[r][c] +
                (T[r][0] * R[c][0] + T[r][1] * R[c][1] + T[r][2] * R[c][2]);

  // inverse via adjugate
  float c00 = G[1][1] * G[2][2] - G[1][2] * G[2][1];
  float c01 = G[1][2] * G[2][0] - G[1][0] * G[2][2];
  float c02 = G[1][0] * G[2][1] - G[1][1] * G[2][0];
  float det = G[0][0] * c00 + G[0][1] * c01 + G[0][2] * c02;
  float rdet = 1.0f / det;
  float i00 = (G[1][1] * G[2][2] - G[1][2] * G[2][1]) * rdet;
  float i01 = (G[0][2] * G[2][1] - G[0][1] * G[2][2]) * rdet;
  float i02 = (G[0][1] * G[1][2] - G[0][2] * G[1][1]) * rdet;
  float i10 = (G[1][2] * G[2][0] - G[1][0] * G[2][2]) * rdet;
  float i11 = (G[0][0] * G[2][2] - G[0][2] * G[2][0]) * rdet;
  float i12 = (G[0][2] * G[1][0] - G[0][0] * G[1][2]) * rdet;
  float i20 = (G[1][0] * G[2][1] - G[1][1] * G[2][0]) * rdet;
  float i21 = (G[0][1] * G[2][0] - G[0][0] * G[2][1]) * rdet;
  float i22 = (G[0][0] * G[1][1] - G[0][1] * G[1][0]) * rdet;

  float dvx = px - ax, dvy = py - ay, dvz = pz - az;
  float t0 = i00 * dvx + i01 * dvy + i02 * dvz;
  float t1 = i10 * dvx + i11 * dvy + i12 * dvz;
  float t2 = i20 * dvx + i21 * dvy + i22 * dvz;
  float sq = dvx * t0 + dvy * t1 + dvz * t2;
  float logdet = logf(det);

  const float* nv = nrm + ((size_t)b * N_ + i) * 3;
  float nx = nv[0], ny = nv[1], nz = nv[2];
  float gx = ax - px, gy = ay - py, gz = az - pz;
  float dt = nx * gx + ny * gy + nz * gz;
  float den = fmaxf(sqrtf(nx * nx + ny * ny + nz * nz) *
                        sqrtf(gx * gx + gy * gy + gz * gz),
                    1e-8f);
  float cs = dt / den;
  float w = cs * cs * cmv;

  double vals[19];
  vals[0] = (double)cmv;
  vals[1] = (double)(sq) * (double)cmv;
  vals[2] = (double)(logdet) * (double)cmv;
  vals[3] = (double)w;
  vals[4] = (double)w * px;
  vals[5] = (double)w * py;
  vals[6] = (double)w * pz;
  vals[7] = (double)w * ax;
  vals[8] = (double)w * ay;
  vals[9] = (double)w * az;
  float pr[3] = {px, py, pz}, ar[3] = {ax, ay, az};
#pragma unroll
  for (int r = 0; r < 3; ++r)
#pragma unroll
    for (int c = 0; c < 3; ++c)
      vals[10 + r * 3 + c] = (double)w * (double)pr[r] * (double)ar[c];

  // wave reduce (64 lanes)
#pragma unroll
  for (int off = 32; off > 0; off >>= 1) {
#pragma unroll
    for (int k = 0; k < 19; ++k) vals[k] += __shfl_down(vals[k], off);
  }
  __shared__ double red[4][19];
  const int lane = threadIdx.x & 63, wv = threadIdx.x >> 6;
  if (lane == 0) {
#pragma unroll
    for (int k = 0; k < 19; ++k) red[wv][k] = vals[k];
  }
  __syncthreads();
  if (threadIdx.x < 19) {
    double s = red[0][threadIdx.x] + red[1][threadIdx.x] +
               red[2][threadIdx.x] + red[3][threadIdx.x];
    atomicAdd(&acc[b * 32 + threadIdx.x], s);
  }
}

// ====================== kernel 4: finalize (loss + Kabsch) =====================
__device__ double det3(const double M[3][3]) {
  return M[0][0] * (M[1][1] * M[2][2] - M[1][2] * M[2][1]) -
         M[0][1] * (M[1][0] * M[2][2] - M[1][2] * M[2][0]) +
         M[0][2] * (M[1][0] * M[2][1] - M[1][1] * M[2][0]);
}

// robust eigenvector of symmetric A for eigenvalue lam: largest cross product
// of rows of (A - lam I)
__device__ void eigvec3(const double A[3][3], double lam, double v[3]) {
  double r[3][3];
#pragma unroll
  for (int i = 0; i < 3; ++i) {
#pragma unroll
    for (int j = 0; j < 3; ++j) r[i][j] = A[i][j];
    r[i][i] -= lam;
  }
  double c01[3] = {r[0][1] * r[1][2] - r[0][2] * r[1][1],
                   r[0][2] * r[1][0] - r[0][0] * r[1][2],
                   r[0][0] * r[1][1] - r[0][1] * r[1][0]};
  double c02[3] = {r[0][1] * r[2][2] - r[0][2] * r[2][1],
                   r[0][2] * r[2][0] - r[0][0] * r[2][2],
                   r[0][0] * r[2][1] - r[0][1] * r[2][0]};
  double c12[3] = {r[1][1] * r[2][2] - r[1][2] * r[2][1],
                   r[1][2] * r[2][0] - r[1][0] * r[2][2],
                   r[1][0] * r[2][1] - r[1][1] * r[2][0]};
  double n01 = c01[0] * c01[0] + c01[1] * c01[1] + c01[2] * c01[2];
  double n02 = c02[0] * c02[0] + c02[1] * c02[1] + c02[2] * c02[2];
  double n12 = c12[0] * c12[0] + c12[1] * c12[1] + c12[2] * c12[2];
  double* best = c01;
  double bn = n01;
  if (n02 > bn) { best = c02; bn = n02; }
  if (n12 > bn) { best = c12; bn = n12; }
  double inv = (bn > 0.0) ? 1.0 / sqrt(bn) : 0.0;
  v[0] = best[0] * inv;
  v[1] = best[1] * inv;
  v[2] = best[2] * inv;
  if (inv == 0.0) v[0] = 1.0;  // degenerate fallback
}

// Kabsch via closed-form symmetric 3x3 eigendecomposition of A = H^T H.
__device__ void kabsch(const double H[3][3], double R[3][3]) {
  double A[3][3];
  for (int i = 0; i < 3; ++i)
    for (int j = 0; j < 3; ++j)
      A[i][j] = H[0][i] * H[0][j] + H[1][i] * H[1][j] + H[2][i] * H[2][j];

  double lam[3];
  double Vs[3][3];
  double mtr = (A[0][0] + A[1][1] + A[2][2]) / 3.0;
  double K00 = A[0][0] - mtr, K11 = A[1][1] - mtr, K22 = A[2][2] - mtr;
  double a01 = A[0][1], a02 = A[0][2], a12 = A[1][2];
  double p2 = K00 * K00 + K11 * K11 + K22 * K22 +
              2.0 * (a01 * a01 + a02 * a02 + a12 * a12);
  double p = sqrt(p2 / 6.0);
  if (p < 1e-100) {
    lam[0] = lam[1] = lam[2] = mtr;
    for (int i = 0; i < 3; ++i)
      for (int j = 0; j < 3; ++j) Vs[i][j] = (i == j) ? 1.0 : 0.0;
  } else {
    double detK = K00 * (K11 * K22 - a12 * a12) -
                  a01 * (a01 * K22 - a12 * a02) +
                  a02 * (a01 * a12 - K11 * a02);
    double rr = detK / (2.0 * p * p * p);
    rr = fmin(1.0, fmax(-1.0, rr));
    double phi = acos(rr) / 3.0;
    lam[0] = mtr + 2.0 * p * cos(phi);                        // largest
    lam[2] = mtr + 2.0 * p * cos(phi + 2.0943951023931953);   // smallest
    lam[1] = 3.0 * mtr - lam[0] - lam[2];                     // middle

    double v0[3], v1[3];
    eigvec3(A, lam[0], v0);
    eigvec3(A, lam[1], v1);
    double dp = v1[0] * v0[0] + v1[1] * v0[1] + v1[2] * v0[2];
    v1[0] -= dp * v0[0];
    v1[1] -= dp * v0[1];
    v1[2] -= dp * v0[2];
    double n1 = v1[0] * v1[0] + v1[1] * v1[1] + v1[2] * v1[2];
    if (n1 > 1e-200) {
      double inv = 1.0 / sqrt(n1);
      v1[0] *= inv; v1[1] *= inv; v1[2] *= inv;
    } else {
      double ax = fabs(v0[0]), ay = fabs(v0[1]), az = fabs(v0[2]);
      double t[3] = {0, 0, 0};
      if (ax <= ay && ax <= az) t[0] = 1.0;
      else if (ay <= az) t[1] = 1.0;
      else t[2] = 1.0;
      v1[0] = v0[1] * t[2] - v0[2] * t[1];
      v1[1] = v0[2] * t[0] - v0[0] * t[2];
      v1[2] = v0[0] * t[1] - v0[1] * t[0];
      double inv = 1.0 / sqrt(v1[0] * v1[0] + v1[1] * v1[1] + v1[2] * v1[2]);
      v1[0] *= inv; v1[1] *= inv; v1[2] *= inv;
    }
    double v2[3] = {v0[1] * v1[2] - v0[2] * v1[1],
                    v0[2] * v1[0] - v0[0] * v1[2],
                    v0[0] * v1[1] - v0[1] * v1[0]};
    for (int i = 0; i < 3; ++i) {
      Vs[i][0] = v0[i];
      Vs[i][1] = v1[i];
      Vs[i][2] = v2[i];
    }
  }

  double sg[3];
  for (int c = 0; c < 3; ++c) sg[c] = sqrt(fmax(lam[c], 0.0));

  double U[3][3];
  for (int c = 0; c < 3; ++c) {
    double ux = H[0][0] * Vs[0][c] + H[0][1] * Vs[1][c] + H[0][2] * Vs[2][c];
    double uy = H[1][0] * Vs[0][c] + H[1][1] * Vs[1][c] + H[1][2] * Vs[2][c];
    double uz = H[2][0] * Vs[0][c] + H[2][1] * Vs[1][c] + H[2][2] * Vs[2][c];
    double inv = (sg[c] > 1e-12 * sg[0] + 1e-300) ? 1.0 / sg[c] : 0.0;
    U[0][c] = ux * inv;
    U[1][c] = uy * inv;
    U[2][c] = uz * inv;
  }
  if (sg[2] <= 1e-12 * sg[0] + 1e-300) {
    U[0][2] = U[1][0] * U[2][1] - U[2][0] * U[1][1];
    U[1][2] = U[2][0] * U[0][1] - U[0][0] * U[2][1];
    U[2][2] = U[0][0] * U[1][1] - U[1][0] * U[0][1];
  }
  double d = det3(U) * det3(Vs);
  for (int i = 0; i < 3; ++i)
    for (int j = 0; j < 3; ++j)
      R[i][j] = Vs[i][0] * U[j][0] + Vs[i][1] * U[j][1] + d * Vs[i][2] * U[j][2];
}

__global__ __launch_bounds__(64) void finalize_kernel(
    const double* __restrict__ acc, float* __restrict__ out) {
  __shared__ double lossb[B_];
  const int b = threadIdx.x;
  if (b < B_) {
    const double* a = acc + b * 32;
    double cnt = a[0], ssq = a[1], sld = a[2], W = a[3];
    double loss = ssq / cnt + 0.001 * 0.5 * sld / cnt;
    lossb[b] = loss;
    double Ss[3] = {a[4], a[5], a[6]}, St[3] = {a[7], a[8], a[9]};
    double sc[3], tc[3];
    for (int c = 0; c < 3; ++c) { sc[c] = Ss[c] / W; tc[c] = St[c] / W; }
    double H[3][3];
    for (int i = 0; i < 3; ++i)
      for (int j = 0; j < 3; ++j)
        H[i][j] = a[10 + i * 3 + j] - Ss[i] * St[j] / W;
    double Rm[3][3];
    kabsch(H, Rm);
    for (int i = 0; i < 3; ++i)
      for (int j = 0; j < 3; ++j)
        out[1 + b * 9 + i * 3 + j] = (float)Rm[i][j];
    for (int i = 0; i < 3; ++i) {
      double t =
          tc[i] - (Rm[i][0] * sc[0] + Rm[i][1] * sc[1] + Rm[i][2] * sc[2]);
      out[1 + B_ * 9 + b * 3 + i] = (float)t;
    }
  }
  __syncthreads();
  if (threadIdx.x == 0) out[0] = (float)(lossb[0] + lossb[1]);
}

// ================================ launcher ====================================
extern "C" void kernel_launch(void* const* d_in, const int* in_sizes, int n_in,
                              void* d_out, int out_size, void* d_ws,
                              size_t ws_size, hipStream_t stream) {
  const float* xyz_pred = (const float*)d_in[0];
  const float* xyz_target = (const float*)d_in[1];
  const float* cov_pred = (const float*)d_in[2];
  const float* cov_target = (const float*)d_in[3];
  const float* R_pred = (const float*)d_in[4];
  // d_in[5] t_pred unused, d_in[7] normal_target unused
  const float* normal_pred = (const float*)d_in[6];
  float* out = (float*)d_out;

  char* ws = (char*)d_ws;
  double* acc = (double*)ws;                                   // B*32 doubles
  unsigned long long* keys = (unsigned long long*)(ws + 512);  // B*N u64
  float* mout = (float*)(ws + 512 + (size_t)B_ * N_ * 8);      // B floats
  float* tnorm = (float*)(ws + 1024 + (size_t)B_ * N_ * 8);    // B*M floats

  hipLaunchKernelGGL(init_kernel, dim3(B_ * M_ / 256), dim3(256), 0, stream,
                     keys, xyz_target, tnorm);
  hipLaunchKernelGGL(nn_kernel, dim3(N_ / PTS, CH, B_), dim3(256), 0, stream,
                     xyz_pred, xyz_target, tnorm, keys);
  hipLaunchKernelGGL(sel_kernel, dim3(B_), dim3(1024), 0, stream, keys, mout,
                     acc);
  hipLaunchKernelGGL(main_kernel, dim3(N_ / 256, B_), dim3(256), 0, stream,
                     xyz_pred, xyz_target, cov_pred, cov_target, R_pred,
                     normal_pred, keys, mout, acc);
  hipLaunchKernelGGL(finalize_kernel, dim3(1), dim3(64), 0, stream, acc, out);
}